// Round 1
// baseline (475.639 us; speedup 1.0000x reference)
//
#include <hip/hip_runtime.h>
#include <math.h>

// Problem constants (match reference)
#define BB    512
#define NN    128
#define OBSD  128
#define MSGD  64
#define NHEAD 4
#define DHEAD 16
#define EHID  128
#define IHID  256
#define TT    32   // tokens per tile for encoder/integrator kernels

// ---------------------------------------------------------------------------
// Kernel 1: msgs = relu(obs@ew1+eb1)@ew2+eb2 ; q/k/v = msgs@W + b  (per token)
// 32-token tile per block, 256 threads. LDS: obsT 18K + hidT 18K + msgT 9K = 45KB
// ---------------------------------------------------------------------------
__global__ __launch_bounds__(256) void k_encoder(
    const float* __restrict__ obs,
    const float* __restrict__ ew1, const float* __restrict__ eb1,
    const float* __restrict__ ew2, const float* __restrict__ eb2,
    const float* __restrict__ wq, const float* __restrict__ bq,
    const float* __restrict__ wk, const float* __restrict__ bk,
    const float* __restrict__ wv, const float* __restrict__ bv,
    float* __restrict__ msgs_out,
    float* __restrict__ qws, float* __restrict__ kws, float* __restrict__ vws)
{
    __shared__ float obsT[OBSD][36];  // [k][token], pad 36 keeps b128 alignment
    __shared__ float hidT[EHID][36];
    __shared__ float msgT[MSGD][36];

    const int tid = threadIdx.x;
    const long tok0 = (long)blockIdx.x * TT;

    // load obs tile (32 x 128) transposed into LDS
    {
        const float4* src = (const float4*)(obs + tok0 * OBSD);
        #pragma unroll
        for (int i = 0; i < 4; ++i) {
            int f = tid + i * 256;          // 0..1023 (32 tok x 32 float4)
            int t = f >> 5;
            int kk = (f & 31) << 2;
            float4 v4 = src[f];
            obsT[kk + 0][t] = v4.x;
            obsT[kk + 1][t] = v4.y;
            obsT[kk + 2][t] = v4.z;
            obsT[kk + 3][t] = v4.w;
        }
    }
    __syncthreads();

    const int ty = tid >> 5;   // 0..7  -> token group of 4
    const int tx = tid & 31;   // 0..31
    const int t0 = ty << 2;

    // ---- GEMM1: hidden = relu(obs @ ew1 + eb1), 32x128, K=128
    {
        const int c0 = tx << 2;
        float acc[4][4] = {};
        #pragma unroll 4
        for (int k = 0; k < OBSD; ++k) {
            const float4 a = *(const float4*)&obsT[k][t0];
            const float4 w = *(const float4*)&ew1[k * EHID + c0];
            const float av[4] = {a.x, a.y, a.z, a.w};
            const float wv4[4] = {w.x, w.y, w.z, w.w};
            #pragma unroll
            for (int i = 0; i < 4; ++i)
                #pragma unroll
                for (int j = 0; j < 4; ++j)
                    acc[i][j] = fmaf(av[i], wv4[j], acc[i][j]);
        }
        const float4 b4 = *(const float4*)&eb1[c0];
        const float bv4[4] = {b4.x, b4.y, b4.z, b4.w};
        #pragma unroll
        for (int j = 0; j < 4; ++j) {
            float4 o;
            o.x = fmaxf(acc[0][j] + bv4[j], 0.0f);
            o.y = fmaxf(acc[1][j] + bv4[j], 0.0f);
            o.z = fmaxf(acc[2][j] + bv4[j], 0.0f);
            o.w = fmaxf(acc[3][j] + bv4[j], 0.0f);
            *(float4*)&hidT[c0 + j][t0] = o;
        }
    }
    __syncthreads();

    // ---- GEMM2: msgs = hidden @ ew2 + eb2, 32x64, K=128
    const int c2 = tx << 1;
    {
        float acc[4][2] = {};
        #pragma unroll 4
        for (int k = 0; k < EHID; ++k) {
            const float4 a = *(const float4*)&hidT[k][t0];
            const float w0 = ew2[k * MSGD + c2];
            const float w1 = ew2[k * MSGD + c2 + 1];
            const float av[4] = {a.x, a.y, a.z, a.w};
            #pragma unroll
            for (int i = 0; i < 4; ++i) {
                acc[i][0] = fmaf(av[i], w0, acc[i][0]);
                acc[i][1] = fmaf(av[i], w1, acc[i][1]);
            }
        }
        const float b0 = eb2[c2], b1 = eb2[c2 + 1];
        #pragma unroll
        for (int i = 0; i < 4; ++i) {
            float m0 = acc[i][0] + b0;
            float m1 = acc[i][1] + b1;
            *(float2*)&msgs_out[(tok0 + t0 + i) * MSGD + c2] = make_float2(m0, m1);
            msgT[c2 + 0][t0 + i] = m0;
            msgT[c2 + 1][t0 + i] = m1;
        }
    }
    __syncthreads();

    // ---- q/k/v projections: 32x64 each, K=64
    const float* Ws[3] = {wq, wk, wv};
    const float* Bs[3] = {bq, bk, bv};
    float* Os[3] = {qws, kws, vws};
    #pragma unroll
    for (int m = 0; m < 3; ++m) {
        float acc[4][2] = {};
        const float* W = Ws[m];
        #pragma unroll 4
        for (int k = 0; k < MSGD; ++k) {
            const float4 a = *(const float4*)&msgT[k][t0];
            const float w0 = W[k * MSGD + c2];
            const float w1 = W[k * MSGD + c2 + 1];
            const float av[4] = {a.x, a.y, a.z, a.w};
            #pragma unroll
            for (int i = 0; i < 4; ++i) {
                acc[i][0] = fmaf(av[i], w0, acc[i][0]);
                acc[i][1] = fmaf(av[i], w1, acc[i][1]);
            }
        }
        const float b0 = Bs[m][c2], b1 = Bs[m][c2 + 1];
        #pragma unroll
        for (int i = 0; i < 4; ++i) {
            *(float2*)&Os[m][(tok0 + t0 + i) * MSGD + c2] =
                make_float2(acc[i][0] + b0, acc[i][1] + b1);
        }
    }
}

// ---------------------------------------------------------------------------
// Kernel 2: attention per batch. 1 block/batch, 4 waves = 4 heads.
// Each lane owns 2 query rows (lane, lane+64); online softmax in registers.
// LDS: K,V slabs 2 x 128x68 = 68KB -> 2 blocks/CU.
// ---------------------------------------------------------------------------
__global__ __launch_bounds__(256) void k_attn(
    const float* __restrict__ qws, const float* __restrict__ kws,
    const float* __restrict__ vws, float* __restrict__ ctxws)
{
    __shared__ float ks[NN][68];
    __shared__ float vs[NN][68];

    const int tid = threadIdx.x;
    const int b = blockIdx.x;
    const float* kb = kws + (long)b * NN * MSGD;
    const float* vb = vws + (long)b * NN * MSGD;

    #pragma unroll
    for (int i = 0; i < 8; ++i) {
        int f = tid + i * 256;          // 0..2047 (128 rows x 16 float4)
        int t = f >> 4;
        int c = (f & 15) << 2;
        *(float4*)&ks[t][c] = ((const float4*)kb)[f];
        *(float4*)&vs[t][c] = ((const float4*)vb)[f];
    }
    __syncthreads();

    const int lane = tid & 63;
    const int h = tid >> 6;         // head = wave id

    const float* qr0 = qws + ((long)b * NN + lane) * MSGD + h * DHEAD;
    const float* qr1 = qr0 + 64 * MSGD;
    float q0[16], q1[16];
    #pragma unroll
    for (int i = 0; i < 4; ++i) {
        float4 a = *(const float4*)(qr0 + 4 * i);
        q0[4*i] = a.x; q0[4*i+1] = a.y; q0[4*i+2] = a.z; q0[4*i+3] = a.w;
        float4 c4 = *(const float4*)(qr1 + 4 * i);
        q1[4*i] = c4.x; q1[4*i+1] = c4.y; q1[4*i+2] = c4.z; q1[4*i+3] = c4.w;
    }

    float m0 = -1e30f, l0 = 0.0f, m1 = -1e30f, l1 = 0.0f;
    float a0[16] = {}, a1[16] = {};

    for (int j = 0; j < NN; ++j) {
        const float* kr = &ks[j][h * DHEAD];
        const float* vr = &vs[j][h * DHEAD];
        float kf[16], vf[16];
        #pragma unroll
        for (int i = 0; i < 4; ++i) {
            float4 kv = *(const float4*)(kr + 4 * i);
            kf[4*i] = kv.x; kf[4*i+1] = kv.y; kf[4*i+2] = kv.z; kf[4*i+3] = kv.w;
            float4 vv = *(const float4*)(vr + 4 * i);
            vf[4*i] = vv.x; vf[4*i+1] = vv.y; vf[4*i+2] = vv.z; vf[4*i+3] = vv.w;
        }
        float s0 = 0.0f, s1 = 0.0f;
        #pragma unroll
        for (int d = 0; d < 16; ++d) {
            s0 = fmaf(q0[d], kf[d], s0);
            s1 = fmaf(q1[d], kf[d], s1);
        }
        s0 *= 0.25f;  // 1/sqrt(16)
        s1 *= 0.25f;
        const float mn0 = fmaxf(m0, s0), mn1 = fmaxf(m1, s1);
        const float e0 = __expf(s0 - mn0), r0 = __expf(m0 - mn0);
        const float e1 = __expf(s1 - mn1), r1 = __expf(m1 - mn1);
        l0 = l0 * r0 + e0;
        l1 = l1 * r1 + e1;
        m0 = mn0; m1 = mn1;
        #pragma unroll
        for (int d = 0; d < 16; ++d) {
            a0[d] = a0[d] * r0 + e0 * vf[d];
            a1[d] = a1[d] * r1 + e1 * vf[d];
        }
    }

    const float il0 = 1.0f / l0;
    const float il1 = 1.0f / l1;
    float* c0p = ctxws + ((long)b * NN + lane) * MSGD + h * DHEAD;
    float* c1p = c0p + 64 * MSGD;
    #pragma unroll
    for (int i = 0; i < 4; ++i) {
        *(float4*)(c0p + 4 * i) = make_float4(a0[4*i] * il0, a0[4*i+1] * il0,
                                              a0[4*i+2] * il0, a0[4*i+3] * il0);
        *(float4*)(c1p + 4 * i) = make_float4(a1[4*i] * il1, a1[4*i+1] * il1,
                                              a1[4*i+2] * il1, a1[4*i+3] * il1);
    }
}

// ---------------------------------------------------------------------------
// Kernel 3: agg = ctx@wo+bo ; comb=[obs,agg] ; h=LN(comb@iw1+ib1);
//           h=relu(h)*... ; out = h@iw2+ib2
// 32-token tile, 256 threads. LDS: combT 27K + hT 36K (ctxT aliases hT) = 63KB
// ---------------------------------------------------------------------------
__global__ __launch_bounds__(256) void k_integrate(
    const float* __restrict__ obs, const float* __restrict__ ctxws,
    const float* __restrict__ wo, const float* __restrict__ bo,
    const float* __restrict__ iw1, const float* __restrict__ ib1,
    const float* __restrict__ lng, const float* __restrict__ lnb,
    const float* __restrict__ iw2, const float* __restrict__ ib2,
    float* __restrict__ out)
{
    __shared__ float combT[OBSD + MSGD][36];  // rows 0..127 obs, 128..191 agg
    __shared__ float hT[IHID][36];
    float (*ctxT)[36] = (float(*)[36])hT;     // ctxT only live before GEMM1

    const int tid = threadIdx.x;
    const long tok0 = (long)blockIdx.x * TT;

    // load obs tile transposed
    {
        const float4* src = (const float4*)(obs + tok0 * OBSD);
        #pragma unroll
        for (int i = 0; i < 4; ++i) {
            int f = tid + i * 256;
            int t = f >> 5;
            int kk = (f & 31) << 2;
            float4 v4 = src[f];
            combT[kk + 0][t] = v4.x;
            combT[kk + 1][t] = v4.y;
            combT[kk + 2][t] = v4.z;
            combT[kk + 3][t] = v4.w;
        }
    }
    // load ctx tile (32 x 64) transposed
    {
        const float4* src = (const float4*)(ctxws + tok0 * MSGD);
        #pragma unroll
        for (int i = 0; i < 2; ++i) {
            int f = tid + i * 256;          // 0..511 (32 tok x 16 float4)
            int t = f >> 4;
            int kk = (f & 15) << 2;
            float4 v4 = src[f];
            ctxT[kk + 0][t] = v4.x;
            ctxT[kk + 1][t] = v4.y;
            ctxT[kk + 2][t] = v4.z;
            ctxT[kk + 3][t] = v4.w;
        }
    }
    __syncthreads();

    const int ty = tid >> 5;
    const int tx = tid & 31;
    const int t0 = ty << 2;

    // ---- agg = ctx @ wo + bo -> combT rows 128..191
    {
        const int c0 = tx << 1;
        float acc[4][2] = {};
        #pragma unroll 4
        for (int k = 0; k < MSGD; ++k) {
            const float4 a = *(const float4*)&ctxT[k][t0];
            const float w0 = wo[k * MSGD + c0];
            const float w1 = wo[k * MSGD + c0 + 1];
            const float av[4] = {a.x, a.y, a.z, a.w};
            #pragma unroll
            for (int i = 0; i < 4; ++i) {
                acc[i][0] = fmaf(av[i], w0, acc[i][0]);
                acc[i][1] = fmaf(av[i], w1, acc[i][1]);
            }
        }
        const float b0 = bo[c0], b1 = bo[c0 + 1];
        float4 o0 = make_float4(acc[0][0] + b0, acc[1][0] + b0,
                                acc[2][0] + b0, acc[3][0] + b0);
        float4 o1 = make_float4(acc[0][1] + b1, acc[1][1] + b1,
                                acc[2][1] + b1, acc[3][1] + b1);
        *(float4*)&combT[OBSD + c0 + 0][t0] = o0;
        *(float4*)&combT[OBSD + c0 + 1][t0] = o1;
    }
    __syncthreads();   // ctxT reads done; hT may now be overwritten

    // ---- GEMM1 (K=192) + bias + LayerNorm + ReLU -> hT
    {
        const int c0 = tx << 3;     // 8 cols per thread
        float acc[4][8] = {};
        #pragma unroll 2
        for (int k = 0; k < OBSD + MSGD; ++k) {
            const float4 a = *(const float4*)&combT[k][t0];
            const float4 w0 = *(const float4*)&iw1[k * IHID + c0];
            const float4 w1 = *(const float4*)&iw1[k * IHID + c0 + 4];
            const float av[4] = {a.x, a.y, a.z, a.w};
            const float wv8[8] = {w0.x, w0.y, w0.z, w0.w, w1.x, w1.y, w1.z, w1.w};
            #pragma unroll
            for (int i = 0; i < 4; ++i)
                #pragma unroll
                for (int j = 0; j < 8; ++j)
                    acc[i][j] = fmaf(av[i], wv8[j], acc[i][j]);
        }
        const float4 bb0 = *(const float4*)&ib1[c0];
        const float4 bb1 = *(const float4*)&ib1[c0 + 4];
        const float bias[8] = {bb0.x, bb0.y, bb0.z, bb0.w, bb1.x, bb1.y, bb1.z, bb1.w};
        const float4 gg0 = *(const float4*)&lng[c0];
        const float4 gg1 = *(const float4*)&lng[c0 + 4];
        const float gv[8] = {gg0.x, gg0.y, gg0.z, gg0.w, gg1.x, gg1.y, gg1.z, gg1.w};
        const float4 ob0 = *(const float4*)&lnb[c0];
        const float4 ob1 = *(const float4*)&lnb[c0 + 4];
        const float obv[8] = {ob0.x, ob0.y, ob0.z, ob0.w, ob1.x, ob1.y, ob1.z, ob1.w};

        #pragma unroll
        for (int i = 0; i < 4; ++i) {
            float s = 0.0f, s2 = 0.0f;
            #pragma unroll
            for (int j = 0; j < 8; ++j) {
                acc[i][j] += bias[j];
                s += acc[i][j];
                s2 = fmaf(acc[i][j], acc[i][j], s2);
            }
            // reduce across the 32 lanes that share this token (same half-wave)
            #pragma unroll
            for (int msk = 1; msk < 32; msk <<= 1) {
                s  += __shfl_xor(s,  msk, 64);
                s2 += __shfl_xor(s2, msk, 64);
            }
            const float mu = s * (1.0f / IHID);
            const float var = s2 * (1.0f / IHID) - mu * mu;
            const float rstd = rsqrtf(var + 1e-5f);
            #pragma unroll
            for (int j = 0; j < 8; ++j)
                acc[i][j] = fmaxf(fmaf((acc[i][j] - mu) * rstd, gv[j], obv[j]), 0.0f);
        }
        #pragma unroll
        for (int j = 0; j < 8; ++j) {
            *(float4*)&hT[c0 + j][t0] =
                make_float4(acc[0][j], acc[1][j], acc[2][j], acc[3][j]);
        }
    }
    __syncthreads();

    // ---- GEMM2: out = h @ iw2 + ib2 (K=256, 32x128)
    {
        const int c0 = tx << 2;
        float acc[4][4] = {};
        #pragma unroll 4
        for (int k = 0; k < IHID; ++k) {
            const float4 a = *(const float4*)&hT[k][t0];
            const float4 w = *(const float4*)&iw2[k * OBSD + c0];
            const float av[4] = {a.x, a.y, a.z, a.w};
            const float wv4[4] = {w.x, w.y, w.z, w.w};
            #pragma unroll
            for (int i = 0; i < 4; ++i)
                #pragma unroll
                for (int j = 0; j < 4; ++j)
                    acc[i][j] = fmaf(av[i], wv4[j], acc[i][j]);
        }
        const float4 b4 = *(const float4*)&ib2[c0];
        const float bv4[4] = {b4.x, b4.y, b4.z, b4.w};
        #pragma unroll
        for (int i = 0; i < 4; ++i) {
            *(float4*)&out[(tok0 + t0 + i) * OBSD + c0] =
                make_float4(acc[i][0] + bv4[0], acc[i][1] + bv4[1],
                            acc[i][2] + bv4[2], acc[i][3] + bv4[3]);
        }
    }
}

// ---------------------------------------------------------------------------
extern "C" void kernel_launch(void* const* d_in, const int* in_sizes, int n_in,
                              void* d_out, int out_size, void* d_ws, size_t ws_size,
                              hipStream_t stream)
{
    (void)in_sizes; (void)n_in; (void)out_size; (void)ws_size;

    const float* obs  = (const float*)d_in[0];
    const float* ew1  = (const float*)d_in[1];
    const float* eb1  = (const float*)d_in[2];
    const float* ew2  = (const float*)d_in[3];
    const float* eb2  = (const float*)d_in[4];
    const float* wq   = (const float*)d_in[5];
    const float* bq   = (const float*)d_in[6];
    const float* wk   = (const float*)d_in[7];
    const float* bk   = (const float*)d_in[8];
    const float* wv   = (const float*)d_in[9];
    const float* bv   = (const float*)d_in[10];
    const float* wo   = (const float*)d_in[11];
    const float* bo   = (const float*)d_in[12];
    const float* iw1  = (const float*)d_in[13];
    const float* ib1  = (const float*)d_in[14];
    const float* lng  = (const float*)d_in[15];
    const float* lnb  = (const float*)d_in[16];
    const float* iw2  = (const float*)d_in[17];
    const float* ib2  = (const float*)d_in[18];

    float* enriched = (float*)d_out;                       // B*N*OBS
    float* msgs     = enriched + (size_t)BB * NN * OBSD;   // B*N*MSG

    // workspace: q, k, v, ctx — 4 * 16.78 MB = 67.1 MB
    float* qws   = (float*)d_ws;
    float* kws   = qws + (size_t)BB * NN * MSGD;
    float* vws   = kws + (size_t)BB * NN * MSGD;
    float* ctxws = vws + (size_t)BB * NN * MSGD;

    const int tiles = BB * NN / TT;   // 2048
    k_encoder<<<tiles, 256, 0, stream>>>(obs, ew1, eb1, ew2, eb2,
                                         wq, bq, wk, bk, wv, bv,
                                         msgs, qws, kws, vws);
    k_attn<<<BB, 256, 0, stream>>>(qws, kws, vws, ctxws);
    k_integrate<<<tiles, 256, 0, stream>>>(obs, ctxws, wo, bo,
                                           iw1, ib1, lng, lnb, iw2, ib2,
                                           enriched);
}

// Round 2
// 226.199 us; speedup vs baseline: 2.1027x; 2.1027x over previous
//
#include <hip/hip_runtime.h>
#include <math.h>

#define BB    512
#define NN    128
#define OBSD  128
#define MSGD  64
#define EHID  128
#define IHID  256

typedef __attribute__((ext_vector_type(8))) short          s16x8;
typedef __attribute__((ext_vector_type(8))) unsigned short u16x8;
typedef __attribute__((ext_vector_type(4))) float          f32x4;

__device__ __forceinline__ unsigned short f2bf(float f) {
    unsigned u = __builtin_bit_cast(unsigned, f);
    return (unsigned short)((u + 0x7fffu + ((u >> 16) & 1u)) >> 16);
}
__device__ __forceinline__ float bf2f(unsigned short b) {
    return __builtin_bit_cast(float, ((unsigned)b) << 16);
}

// ---------------------------------------------------------------------------
// prep1: fold linear layers (fp32):
//   WqP = ew2@wq, WkP = ew2@wk, WvP = ew2@wv          (128x64 each)
//   WfP = wo@iw1[128:]                                 (64x256)
//   bcat = [eb2 | bq+eb2@wq | bk+eb2@wk | bv+eb2@wv]   (256)
//   bfold = ib1 + bo@iw1[128:]                         (256)
// ws fp32 layout: WqP@0, WkP@8192, WvP@16384, WfP@24576, bcat@40960, bfold@41216
// ---------------------------------------------------------------------------
__global__ __launch_bounds__(256) void k_prep1(
    const float* __restrict__ ew2, const float* __restrict__ eb2,
    const float* __restrict__ wq, const float* __restrict__ bq,
    const float* __restrict__ wk, const float* __restrict__ bk,
    const float* __restrict__ wv, const float* __restrict__ bv,
    const float* __restrict__ wo, const float* __restrict__ bo,
    const float* __restrict__ iw1, const float* __restrict__ ib1,
    float* __restrict__ wsf)
{
    int idx = blockIdx.x * 256 + threadIdx.x;
    if (idx >= 41472) return;
    if (idx < 24576) {
        // WqP/WkP/WvP: [k][n] = sum_m ew2[k][m] * w[m][n]
        const float* W = (idx < 8192) ? wq : (idx < 16384) ? wk : wv;
        int t = idx & 8191;
        int k = t >> 6, n = t & 63;
        float s = 0.0f;
        for (int m = 0; m < 64; ++m) s = fmaf(ew2[k * 64 + m], W[m * 64 + n], s);
        wsf[idx] = s;
    } else if (idx < 40960) {
        int t = idx - 24576;
        int k = t >> 8, n = t & 255;
        float s = 0.0f;
        for (int m = 0; m < 64; ++m) s = fmaf(wo[k * 64 + m], iw1[(128 + m) * 256 + n], s);
        wsf[idx] = s;
    } else if (idx < 41216) {
        int n = idx - 40960;
        float s;
        if (n < 64) s = eb2[n];
        else {
            int c = n & 63;
            const float* W = (n < 128) ? wq : (n < 192) ? wk : wv;
            const float* bb = (n < 128) ? bq : (n < 192) ? bk : bv;
            s = bb[c];
            for (int m = 0; m < 64; ++m) s = fmaf(eb2[m], W[m * 64 + c], s);
        }
        wsf[idx] = s;
    } else {
        int n = idx - 41216;
        float s = ib1[n];
        for (int m = 0; m < 64; ++m) s = fmaf(bo[m], iw1[(128 + m) * 256 + n], s);
        wsf[idx] = s;
    }
}

// ---------------------------------------------------------------------------
// prep2: swizzle weights into bf16 MFMA fragment-linear layout.
// For matrix W (K x N): frag[((kk*NT + nt)*64 + lane)*8 + j] =
//   bf16( W[kk*32 + (lane>>4)*8 + j][nt*16 + (lane&15)] )
// ushort layout (after 41472 floats): ew1s@0(16384) wcats@16384(32768)
//   iw1ts@49152(32768) wfs@81920(16384) iw2s@98304(32768)
// grid: 256 blocks x 512 threads; block -> one (matrix, kk, nt) tile
// ---------------------------------------------------------------------------
__global__ __launch_bounds__(512) void k_prep2(
    const float* __restrict__ ew1, const float* __restrict__ ew2,
    const float* __restrict__ iw1, const float* __restrict__ iw2,
    const float* __restrict__ wsf, unsigned short* __restrict__ wsu)
{
    int b = blockIdx.x, t = threadIdx.x;
    int l = t >> 3, j = t & 7;
    int c = l & 15, g = l >> 4;
    float v;
    unsigned short* dst;
    if (b < 32) {              // ew1s: K=128 N=128, NT=8
        int kk = b >> 3, nt = b & 7;
        int k = kk * 32 + g * 8 + j, n = nt * 16 + c;
        v = ew1[k * 128 + n];
        dst = wsu + b * 512;
    } else if (b < 96) {       // wcats: K=128 N=256 (ew2 | WqP | WkP | WvP)
        int tt = b - 32;
        int kk = tt >> 4, nt = tt & 15;
        int k = kk * 32 + g * 8 + j, n = nt * 16 + c;
        if (n < 64)       v = ew2[k * 64 + n];
        else if (n < 128) v = wsf[0     + k * 64 + (n - 64)];
        else if (n < 192) v = wsf[8192  + k * 64 + (n - 128)];
        else              v = wsf[16384 + k * 64 + (n - 192)];
        dst = wsu + 16384 + tt * 512;
    } else if (b < 160) {      // iw1ts: K=128 N=256 (top rows of iw1)
        int tt = b - 96;
        int kk = tt >> 4, nt = tt & 15;
        int k = kk * 32 + g * 8 + j, n = nt * 16 + c;
        v = iw1[k * 256 + n];
        dst = wsu + 49152 + tt * 512;
    } else if (b < 192) {      // wfs: K=64 N=256 (WfP)
        int tt = b - 160;
        int kk = tt >> 4, nt = tt & 15;
        int k = kk * 32 + g * 8 + j, n = nt * 16 + c;
        v = wsf[24576 + k * 256 + n];
        dst = wsu + 81920 + tt * 512;
    } else {                   // iw2s: K=256 N=128
        int tt = b - 192;
        int kk = tt >> 3, nt = tt & 7;
        int k = kk * 32 + g * 8 + j, n = nt * 16 + c;
        v = iw2[k * 128 + n];
        dst = wsu + 98304 + tt * 512;
    }
    dst[l * 8 + j] = f2bf(v);
}

// ---------------------------------------------------------------------------
// k_encoder: hid = relu(obs@ew1+eb1); [msgs|q|k|v] = hid@Wcat + bcat
// 4 waves/block, 16 tokens/wave. MFMA 16x16x32 bf16.
// ---------------------------------------------------------------------------
__global__ __launch_bounds__(256) void k_encoder(
    const float* __restrict__ obs, const unsigned short* __restrict__ ew1s,
    const float* __restrict__ eb1, const unsigned short* __restrict__ wcats,
    const float* __restrict__ bcat, float* __restrict__ msgs_out,
    unsigned short* __restrict__ qws, unsigned short* __restrict__ kws,
    unsigned short* __restrict__ vws)
{
    __shared__ unsigned short hls[4][16][136];   // wave-private 16x128 (+8 pad)
    const int tid = threadIdx.x, lane = tid & 63, w = tid >> 6;
    const int row = lane & 15, g = lane >> 4;
    const long tok0 = (long)blockIdx.x * 64 + w * 16;

    // A-fragments (obs fp32 -> bf16): row = lane&15, k = kk*32 + g*8 + j
    s16x8 afr[4];
    {
        const float* ap = obs + (tok0 + row) * OBSD + g * 8;
        #pragma unroll
        for (int kk = 0; kk < 4; ++kk) {
            float4 x0 = *(const float4*)(ap + kk * 32);
            float4 x1 = *(const float4*)(ap + kk * 32 + 4);
            s16x8 a;
            a[0] = f2bf(x0.x); a[1] = f2bf(x0.y); a[2] = f2bf(x0.z); a[3] = f2bf(x0.w);
            a[4] = f2bf(x1.x); a[5] = f2bf(x1.y); a[6] = f2bf(x1.z); a[7] = f2bf(x1.w);
            afr[kk] = a;
        }
    }
    f32x4 acc1[8];
    #pragma unroll
    for (int nt = 0; nt < 8; ++nt) acc1[nt] = (f32x4){0.f, 0.f, 0.f, 0.f};
    #pragma unroll
    for (int kk = 0; kk < 4; ++kk)
        #pragma unroll
        for (int nt = 0; nt < 8; ++nt) {
            s16x8 b = *(const s16x8*)&ew1s[(((kk << 3) + nt) * 64 + lane) * 8];
            acc1[nt] = __builtin_amdgcn_mfma_f32_16x16x32_bf16(afr[kk], b, acc1[nt], 0, 0, 0);
        }
    // bias + relu -> LDS row-major bf16 (D-layout: tokrow = g*4+r, col = nt*16+row)
    #pragma unroll
    for (int nt = 0; nt < 8; ++nt) {
        float bias = eb1[nt * 16 + row];
        #pragma unroll
        for (int r = 0; r < 4; ++r)
            hls[w][g * 4 + r][nt * 16 + row] = f2bf(fmaxf(acc1[nt][r] + bias, 0.f));
    }
    __syncthreads();

    f32x4 acc2[16];
    #pragma unroll
    for (int nt = 0; nt < 16; ++nt) acc2[nt] = (f32x4){0.f, 0.f, 0.f, 0.f};
    #pragma unroll
    for (int kk = 0; kk < 4; ++kk) {
        s16x8 a = *(const s16x8*)&hls[w][row][kk * 32 + g * 8];
        #pragma unroll
        for (int nt = 0; nt < 16; ++nt) {
            s16x8 b = *(const s16x8*)&wcats[(((kk << 4) + nt) * 64 + lane) * 8];
            acc2[nt] = __builtin_amdgcn_mfma_f32_16x16x32_bf16(a, b, acc2[nt], 0, 0, 0);
        }
    }
    #pragma unroll
    for (int nt = 0; nt < 16; ++nt) {
        int col = nt * 16 + row;
        float bias = bcat[col];
        #pragma unroll
        for (int r = 0; r < 4; ++r) {
            long trow = tok0 + g * 4 + r;
            float v = acc2[nt][r] + bias;
            if (nt < 4)       msgs_out[trow * MSGD + col] = v;
            else if (nt < 8)  qws[trow * MSGD + (col - 64)]  = f2bf(v);
            else if (nt < 12) kws[trow * MSGD + (col - 128)] = f2bf(v);
            else              vws[trow * MSGD + (col - 192)] = f2bf(v);
        }
    }
}

// ---------------------------------------------------------------------------
// k_attn: per-batch flash attention, fp32 online softmax, bf16 q/k/v.
// 1 block/batch, 4 waves = 4 heads, lane owns rows {lane, lane+64}.
// ---------------------------------------------------------------------------
__global__ __launch_bounds__(256) void k_attn(
    const unsigned short* __restrict__ qws, const unsigned short* __restrict__ kws,
    const unsigned short* __restrict__ vws, unsigned short* __restrict__ ctxws)
{
    __shared__ float ks[NN][68];
    __shared__ float vs[NN][68];
    const int tid = threadIdx.x, b = blockIdx.x;
    const unsigned short* kb = kws + (long)b * NN * MSGD;
    const unsigned short* vb = vws + (long)b * NN * MSGD;

    #pragma unroll
    for (int i = 0; i < 4; ++i) {
        int f = tid + i * 256;      // 0..1023: row=f>>3, chunk=(f&7)*8 ushorts
        int t = f >> 3, c = (f & 7) * 8;
        u16x8 k8 = ((const u16x8*)kb)[f];
        u16x8 v8 = ((const u16x8*)vb)[f];
        #pragma unroll
        for (int j = 0; j < 8; ++j) { ks[t][c + j] = bf2f(k8[j]); vs[t][c + j] = bf2f(v8[j]); }
    }
    __syncthreads();

    const int lane = tid & 63, h = tid >> 6;
    const unsigned short* qr0 = qws + ((long)b * NN + lane) * MSGD + h * 16;
    const unsigned short* qr1 = qr0 + 64 * MSGD;
    float q0[16], q1[16];
    {
        u16x8 a0 = *(const u16x8*)qr0, a1 = *(const u16x8*)(qr0 + 8);
        u16x8 c0 = *(const u16x8*)qr1, c1 = *(const u16x8*)(qr1 + 8);
        #pragma unroll
        for (int j = 0; j < 8; ++j) {
            q0[j] = bf2f(a0[j]); q0[8 + j] = bf2f(a1[j]);
            q1[j] = bf2f(c0[j]); q1[8 + j] = bf2f(c1[j]);
        }
    }

    float m0 = -1e30f, l0 = 0.0f, m1 = -1e30f, l1 = 0.0f;
    float a0[16] = {}, a1[16] = {};
    for (int j = 0; j < NN; ++j) {
        const float* kr = &ks[j][h * 16];
        const float* vr = &vs[j][h * 16];
        float kf[16], vf[16];
        #pragma unroll
        for (int i = 0; i < 4; ++i) {
            float4 kv = *(const float4*)(kr + 4 * i);
            kf[4*i] = kv.x; kf[4*i+1] = kv.y; kf[4*i+2] = kv.z; kf[4*i+3] = kv.w;
            float4 vv = *(const float4*)(vr + 4 * i);
            vf[4*i] = vv.x; vf[4*i+1] = vv.y; vf[4*i+2] = vv.z; vf[4*i+3] = vv.w;
        }
        float s0 = 0.0f, s1 = 0.0f;
        #pragma unroll
        for (int d = 0; d < 16; ++d) {
            s0 = fmaf(q0[d], kf[d], s0);
            s1 = fmaf(q1[d], kf[d], s1);
        }
        s0 *= 0.25f; s1 *= 0.25f;
        const float mn0 = fmaxf(m0, s0), mn1 = fmaxf(m1, s1);
        const float e0 = __expf(s0 - mn0), r0 = __expf(m0 - mn0);
        const float e1 = __expf(s1 - mn1), r1 = __expf(m1 - mn1);
        l0 = l0 * r0 + e0; l1 = l1 * r1 + e1;
        m0 = mn0; m1 = mn1;
        #pragma unroll
        for (int d = 0; d < 16; ++d) {
            a0[d] = a0[d] * r0 + e0 * vf[d];
            a1[d] = a1[d] * r1 + e1 * vf[d];
        }
    }
    const float il0 = 1.0f / l0, il1 = 1.0f / l1;
    unsigned short* c0p = ctxws + ((long)b * NN + lane) * MSGD + h * 16;
    unsigned short* c1p = c0p + 64 * MSGD;
    u16x8 o0a, o0b, o1a, o1b;
    #pragma unroll
    for (int j = 0; j < 8; ++j) {
        o0a[j] = f2bf(a0[j] * il0); o0b[j] = f2bf(a0[8 + j] * il0);
        o1a[j] = f2bf(a1[j] * il1); o1b[j] = f2bf(a1[8 + j] * il1);
    }
    *(u16x8*)c0p = o0a; *(u16x8*)(c0p + 8) = o0b;
    *(u16x8*)c1p = o1a; *(u16x8*)(c1p + 8) = o1b;
}

// ---------------------------------------------------------------------------
// k_integrate: h = LN(obs@iw1_top + ctx@W_fold + b_fold); relu;
//              out = h@iw2 + ib2. MFMA 16x16x32 bf16, LN via 16-lane shfl.
// ---------------------------------------------------------------------------
__global__ __launch_bounds__(256) void k_integrate(
    const float* __restrict__ obs, const unsigned short* __restrict__ ctxws,
    const unsigned short* __restrict__ iw1ts, const unsigned short* __restrict__ wfs,
    const float* __restrict__ bfold, const float* __restrict__ lng,
    const float* __restrict__ lnb, const unsigned short* __restrict__ iw2s,
    const float* __restrict__ ib2, float* __restrict__ out)
{
    __shared__ unsigned short hls[4][16][264];   // wave-private 16x256 (+8 pad)
    const int tid = threadIdx.x, lane = tid & 63, w = tid >> 6;
    const int row = lane & 15, g = lane >> 4;
    const long tok0 = (long)blockIdx.x * 64 + w * 16;

    f32x4 acc[16];
    #pragma unroll
    for (int nt = 0; nt < 16; ++nt) acc[nt] = (f32x4){0.f, 0.f, 0.f, 0.f};

    // obs part (K=128)
    {
        const float* ap = obs + (tok0 + row) * OBSD + g * 8;
        #pragma unroll
        for (int kk = 0; kk < 4; ++kk) {
            float4 x0 = *(const float4*)(ap + kk * 32);
            float4 x1 = *(const float4*)(ap + kk * 32 + 4);
            s16x8 a;
            a[0] = f2bf(x0.x); a[1] = f2bf(x0.y); a[2] = f2bf(x0.z); a[3] = f2bf(x0.w);
            a[4] = f2bf(x1.x); a[5] = f2bf(x1.y); a[6] = f2bf(x1.z); a[7] = f2bf(x1.w);
            #pragma unroll
            for (int nt = 0; nt < 16; ++nt) {
                s16x8 b = *(const s16x8*)&iw1ts[(((kk << 4) + nt) * 64 + lane) * 8];
                acc[nt] = __builtin_amdgcn_mfma_f32_16x16x32_bf16(a, b, acc[nt], 0, 0, 0);
            }
        }
    }
    // ctx part (K=64)
    {
        const unsigned short* cp = ctxws + (tok0 + row) * MSGD + g * 8;
        #pragma unroll
        for (int kk = 0; kk < 2; ++kk) {
            s16x8 a = *(const s16x8*)(cp + kk * 32);
            #pragma unroll
            for (int nt = 0; nt < 16; ++nt) {
                s16x8 b = *(const s16x8*)&wfs[(((kk << 4) + nt) * 64 + lane) * 8];
                acc[nt] = __builtin_amdgcn_mfma_f32_16x16x32_bf16(a, b, acc[nt], 0, 0, 0);
            }
        }
    }

    // bias + LayerNorm + ReLU -> LDS bf16
    float xs[4] = {}, xs2[4] = {};
    #pragma unroll
    for (int nt = 0; nt < 16; ++nt) {
        float bias = bfold[nt * 16 + row];
        #pragma unroll
        for (int r = 0; r < 4; ++r) {
            float v = acc[nt][r] + bias;
            acc[nt][r] = v;
            xs[r] += v;
            xs2[r] = fmaf(v, v, xs2[r]);
        }
    }
    #pragma unroll
    for (int r = 0; r < 4; ++r) {
        #pragma unroll
        for (int m = 1; m < 16; m <<= 1) {
            xs[r]  += __shfl_xor(xs[r],  m, 64);
            xs2[r] += __shfl_xor(xs2[r], m, 64);
        }
    }
    float mu[4], rstd[4];
    #pragma unroll
    for (int r = 0; r < 4; ++r) {
        mu[r] = xs[r] * (1.0f / IHID);
        float var = xs2[r] * (1.0f / IHID) - mu[r] * mu[r];
        rstd[r] = rsqrtf(var + 1e-5f);
    }
    #pragma unroll
    for (int nt = 0; nt < 16; ++nt) {
        float gg = lng[nt * 16 + row], bb = lnb[nt * 16 + row];
        #pragma unroll
        for (int r = 0; r < 4; ++r) {
            float v = fmaf((acc[nt][r] - mu[r]) * rstd[r], gg, bb);
            hls[w][g * 4 + r][nt * 16 + row] = f2bf(fmaxf(v, 0.f));
        }
    }
    __syncthreads();

    // GEMM2: out = h @ iw2 + ib2 (K=256, N=128)
    f32x4 acc2[8];
    #pragma unroll
    for (int nt = 0; nt < 8; ++nt) acc2[nt] = (f32x4){0.f, 0.f, 0.f, 0.f};
    #pragma unroll
    for (int kk = 0; kk < 8; ++kk) {
        s16x8 a = *(const s16x8*)&hls[w][row][kk * 32 + g * 8];
        #pragma unroll
        for (int nt = 0; nt < 8; ++nt) {
            s16x8 b = *(const s16x8*)&iw2s[(((kk << 3) + nt) * 64 + lane) * 8];
            acc2[nt] = __builtin_amdgcn_mfma_f32_16x16x32_bf16(a, b, acc2[nt], 0, 0, 0);
        }
    }
    #pragma unroll
    for (int nt = 0; nt < 8; ++nt) {
        int col = nt * 16 + row;
        float bias = ib2[col];
        #pragma unroll
        for (int r = 0; r < 4; ++r)
            out[(tok0 + g * 4 + r) * OBSD + col] = acc2[nt][r] + bias;
    }
}

// ---------------------------------------------------------------------------
extern "C" void kernel_launch(void* const* d_in, const int* in_sizes, int n_in,
                              void* d_out, int out_size, void* d_ws, size_t ws_size,
                              hipStream_t stream)
{
    (void)in_sizes; (void)n_in; (void)out_size; (void)ws_size;

    const float* obs = (const float*)d_in[0];
    const float* ew1 = (const float*)d_in[1];
    const float* eb1 = (const float*)d_in[2];
    const float* ew2 = (const float*)d_in[3];
    const float* eb2 = (const float*)d_in[4];
    const float* wq  = (const float*)d_in[5];
    const float* bq  = (const float*)d_in[6];
    const float* wk  = (const float*)d_in[7];
    const float* bk  = (const float*)d_in[8];
    const float* wv  = (const float*)d_in[9];
    const float* bv  = (const float*)d_in[10];
    const float* wo  = (const float*)d_in[11];
    const float* bo  = (const float*)d_in[12];
    const float* iw1 = (const float*)d_in[13];
    const float* ib1 = (const float*)d_in[14];
    const float* lng = (const float*)d_in[15];
    const float* lnb = (const float*)d_in[16];
    const float* iw2 = (const float*)d_in[17];
    const float* ib2 = (const float*)d_in[18];

    float* enriched = (float*)d_out;                      // B*N*OBS fp32
    float* msgs     = enriched + (size_t)BB * NN * OBSD;  // B*N*MSG fp32

    // workspace layout
    float* wsf = (float*)d_ws;                            // 41472 floats (folds)
    unsigned short* wsu = (unsigned short*)(wsf + 41472); // swizzled weights
    unsigned short* ew1s  = wsu;
    unsigned short* wcats = wsu + 16384;
    unsigned short* iw1ts = wsu + 49152;
    unsigned short* wfs   = wsu + 81920;
    unsigned short* iw2s  = wsu + 98304;
    unsigned short* qws   = wsu + 131072;                 // activations bf16
    unsigned short* kws   = qws + (size_t)BB * NN * MSGD;
    unsigned short* vws   = kws + (size_t)BB * NN * MSGD;
    unsigned short* ctxws = vws + (size_t)BB * NN * MSGD;

    const float* bcat  = wsf + 40960;
    const float* bfold = wsf + 41216;

    k_prep1<<<162, 256, 0, stream>>>(ew2, eb2, wq, bq, wk, bk, wv, bv,
                                     wo, bo, iw1, ib1, wsf);
    k_prep2<<<256, 512, 0, stream>>>(ew1, ew2, iw1, iw2, wsf, wsu);
    k_encoder<<<BB * NN / 64, 256, 0, stream>>>(obs, ew1s, eb1, wcats, bcat,
                                                msgs, qws, kws, vws);
    k_attn<<<BB, 256, 0, stream>>>(qws, kws, vws, ctxws);
    k_integrate<<<BB * NN / 64, 256, 0, stream>>>(obs, ctxws, iw1ts, wfs, bfold,
                                                  lng, lnb, iw2s, ib2, enriched);
}

// Round 4
// 189.155 us; speedup vs baseline: 2.5145x; 1.1958x over previous
//
#include <hip/hip_runtime.h>
#include <math.h>

#define BB    512
#define NN    128
#define OBSD  128
#define MSGD  64
#define EHID  128
#define IHID  256

typedef __attribute__((ext_vector_type(8))) short          s16x8;
typedef __attribute__((ext_vector_type(4))) short          s16x4;
typedef __attribute__((ext_vector_type(8))) unsigned short u16x8;
typedef __attribute__((ext_vector_type(4))) unsigned short u16x4;
typedef __attribute__((ext_vector_type(4))) float          f32x4;

__device__ __forceinline__ unsigned short f2bf(float f) {
    unsigned u = __builtin_bit_cast(unsigned, f);
    return (unsigned short)((u + 0x7fffu + ((u >> 16) & 1u)) >> 16);
}
__device__ __forceinline__ float bf2f(unsigned short b) {
    return __builtin_bit_cast(float, ((unsigned)b) << 16);
}

// 16x16x16 bf16 MFMA: builtin if present, else inline asm
#if defined(__has_builtin) && __has_builtin(__builtin_amdgcn_mfma_f32_16x16x16bf16_1k)
__device__ __forceinline__ f32x4 MFMA16(s16x4 a, s16x4 b, f32x4 c) {
    return __builtin_amdgcn_mfma_f32_16x16x16bf16_1k(a, b, c, 0, 0, 0);
}
#else
__device__ __forceinline__ f32x4 MFMA16(s16x4 a, s16x4 b, f32x4 c) {
    f32x4 d;
    asm volatile("v_mfma_f32_16x16x16_bf16 %0, %1, %2, %3\n\ts_nop 7\n\ts_nop 7"
                 : "=v"(d) : "v"(a), "v"(b), "v"(c));
    return d;
}
#endif

// ---------------------------------------------------------------------------
// prep1: fold linear layers (fp32):
//   WqP = ew2@wq, WkP = ew2@wk, WvP = ew2@wv          (128x64 each)
//   WfP = wo@iw1[128:]                                 (64x256)
//   bcat = [eb2 | bq+eb2@wq | bk+eb2@wk | bv+eb2@wv]   (256)
//   bfold = ib1 + bo@iw1[128:]                         (256)
// ws fp32 layout: WqP@0, WkP@8192, WvP@16384, WfP@24576, bcat@40960, bfold@41216
// ---------------------------------------------------------------------------
__global__ __launch_bounds__(256) void k_prep1(
    const float* __restrict__ ew2, const float* __restrict__ eb2,
    const float* __restrict__ wq, const float* __restrict__ bq,
    const float* __restrict__ wk, const float* __restrict__ bk,
    const float* __restrict__ wv, const float* __restrict__ bv,
    const float* __restrict__ wo, const float* __restrict__ bo,
    const float* __restrict__ iw1, const float* __restrict__ ib1,
    float* __restrict__ wsf)
{
    int idx = blockIdx.x * 256 + threadIdx.x;
    if (idx >= 41472) return;
    if (idx < 24576) {
        const float* W = (idx < 8192) ? wq : (idx < 16384) ? wk : wv;
        int t = idx & 8191;
        int k = t >> 6, n = t & 63;
        float s = 0.0f;
        for (int m = 0; m < 64; ++m) s = fmaf(ew2[k * 64 + m], W[m * 64 + n], s);
        wsf[idx] = s;
    } else if (idx < 40960) {
        int t = idx - 24576;
        int k = t >> 8, n = t & 255;
        float s = 0.0f;
        for (int m = 0; m < 64; ++m) s = fmaf(wo[k * 64 + m], iw1[(128 + m) * 256 + n], s);
        wsf[idx] = s;
    } else if (idx < 41216) {
        int n = idx - 40960;
        float s;
        if (n < 64) s = eb2[n];
        else {
            int c = n & 63;
            const float* W = (n < 128) ? wq : (n < 192) ? wk : wv;
            const float* bb = (n < 128) ? bq : (n < 192) ? bk : bv;
            s = bb[c];
            for (int m = 0; m < 64; ++m) s = fmaf(eb2[m], W[m * 64 + c], s);
        }
        wsf[idx] = s;
    } else {
        int n = idx - 41216;
        float s = ib1[n];
        for (int m = 0; m < 64; ++m) s = fmaf(bo[m], iw1[(128 + m) * 256 + n], s);
        wsf[idx] = s;
    }
}

// ---------------------------------------------------------------------------
// prep2: swizzle weights into bf16 MFMA fragment-linear layout.
// For matrix W (K x N): frag[((kk*NT + nt)*64 + lane)*8 + j] =
//   bf16( W[kk*32 + (lane>>4)*8 + j][nt*16 + (lane&15)] )
// ushort layout (after 41472 floats): ew1s@0(16384) wcats@16384(32768)
//   iw1ts@49152(32768) wfs@81920(16384) iw2s@98304(32768)
// ---------------------------------------------------------------------------
__global__ __launch_bounds__(512) void k_prep2(
    const float* __restrict__ ew1, const float* __restrict__ ew2,
    const float* __restrict__ iw1, const float* __restrict__ iw2,
    const float* __restrict__ wsf, unsigned short* __restrict__ wsu)
{
    int b = blockIdx.x, t = threadIdx.x;
    int l = t >> 3, j = t & 7;
    int c = l & 15, g = l >> 4;
    float v;
    unsigned short* dst;
    if (b < 32) {              // ew1s: K=128 N=128, NT=8
        int kk = b >> 3, nt = b & 7;
        int k = kk * 32 + g * 8 + j, n = nt * 16 + c;
        v = ew1[k * 128 + n];
        dst = wsu + b * 512;
    } else if (b < 96) {       // wcats: K=128 N=256 (ew2 | WqP | WkP | WvP)
        int tt = b - 32;
        int kk = tt >> 4, nt = tt & 15;
        int k = kk * 32 + g * 8 + j, n = nt * 16 + c;
        if (n < 64)       v = ew2[k * 64 + n];
        else if (n < 128) v = wsf[0     + k * 64 + (n - 64)];
        else if (n < 192) v = wsf[8192  + k * 64 + (n - 128)];
        else              v = wsf[16384 + k * 64 + (n - 192)];
        dst = wsu + 16384 + tt * 512;
    } else if (b < 160) {      // iw1ts: K=128 N=256 (top rows of iw1)
        int tt = b - 96;
        int kk = tt >> 4, nt = tt & 15;
        int k = kk * 32 + g * 8 + j, n = nt * 16 + c;
        v = iw1[k * 256 + n];
        dst = wsu + 49152 + tt * 512;
    } else if (b < 192) {      // wfs: K=64 N=256 (WfP)
        int tt = b - 160;
        int kk = tt >> 4, nt = tt & 15;
        int k = kk * 32 + g * 8 + j, n = nt * 16 + c;
        v = wsf[24576 + k * 256 + n];
        dst = wsu + 81920 + tt * 512;
    } else {                   // iw2s: K=256 N=128
        int tt = b - 192;
        int kk = tt >> 3, nt = tt & 7;
        int k = kk * 32 + g * 8 + j, n = nt * 16 + c;
        v = iw2[k * 128 + n];
        dst = wsu + 98304 + tt * 512;
    }
    dst[l * 8 + j] = f2bf(v);
}

// ---------------------------------------------------------------------------
// k_encoder: hid = relu(obs@ew1+eb1); [msgs|q|k|v] = hid@Wcat + bcat
// 4 waves/block, 16 tokens/wave. MFMA 16x16x32 bf16.
// ---------------------------------------------------------------------------
__global__ __launch_bounds__(256) void k_encoder(
    const float* __restrict__ obs, const unsigned short* __restrict__ ew1s,
    const float* __restrict__ eb1, const unsigned short* __restrict__ wcats,
    const float* __restrict__ bcat, float* __restrict__ msgs_out,
    unsigned short* __restrict__ qws, unsigned short* __restrict__ kws,
    unsigned short* __restrict__ vws)
{
    __shared__ unsigned short hls[4][16][136];
    const int tid = threadIdx.x, lane = tid & 63, w = tid >> 6;
    const int row = lane & 15, g = lane >> 4;
    const long tok0 = (long)blockIdx.x * 64 + w * 16;

    s16x8 afr[4];
    {
        const float* ap = obs + (tok0 + row) * OBSD + g * 8;
        #pragma unroll
        for (int kk = 0; kk < 4; ++kk) {
            float4 x0 = *(const float4*)(ap + kk * 32);
            float4 x1 = *(const float4*)(ap + kk * 32 + 4);
            s16x8 a;
            a[0] = f2bf(x0.x); a[1] = f2bf(x0.y); a[2] = f2bf(x0.z); a[3] = f2bf(x0.w);
            a[4] = f2bf(x1.x); a[5] = f2bf(x1.y); a[6] = f2bf(x1.z); a[7] = f2bf(x1.w);
            afr[kk] = a;
        }
    }
    f32x4 acc1[8];
    #pragma unroll
    for (int nt = 0; nt < 8; ++nt) acc1[nt] = (f32x4){0.f, 0.f, 0.f, 0.f};
    #pragma unroll
    for (int kk = 0; kk < 4; ++kk)
        #pragma unroll
        for (int nt = 0; nt < 8; ++nt) {
            s16x8 b = *(const s16x8*)&ew1s[(((kk << 3) + nt) * 64 + lane) * 8];
            acc1[nt] = __builtin_amdgcn_mfma_f32_16x16x32_bf16(afr[kk], b, acc1[nt], 0, 0, 0);
        }
    #pragma unroll
    for (int nt = 0; nt < 8; ++nt) {
        float bias = eb1[nt * 16 + row];
        #pragma unroll
        for (int r = 0; r < 4; ++r)
            hls[w][g * 4 + r][nt * 16 + row] = f2bf(fmaxf(acc1[nt][r] + bias, 0.f));
    }
    __syncthreads();

    f32x4 acc2[16];
    #pragma unroll
    for (int nt = 0; nt < 16; ++nt) acc2[nt] = (f32x4){0.f, 0.f, 0.f, 0.f};
    #pragma unroll
    for (int kk = 0; kk < 4; ++kk) {
        s16x8 a = *(const s16x8*)&hls[w][row][kk * 32 + g * 8];
        #pragma unroll
        for (int nt = 0; nt < 16; ++nt) {
            s16x8 b = *(const s16x8*)&wcats[(((kk << 4) + nt) * 64 + lane) * 8];
            acc2[nt] = __builtin_amdgcn_mfma_f32_16x16x32_bf16(a, b, acc2[nt], 0, 0, 0);
        }
    }
    #pragma unroll
    for (int nt = 0; nt < 16; ++nt) {
        int col = nt * 16 + row;
        float bias = bcat[col];
        #pragma unroll
        for (int r = 0; r < 4; ++r) {
            long trow = tok0 + g * 4 + r;
            float v = acc2[nt][r] + bias;
            if (nt < 4)       msgs_out[trow * MSGD + col] = v;
            else if (nt < 8)  qws[trow * MSGD + (col - 64)]  = f2bf(v);
            else if (nt < 12) kws[trow * MSGD + (col - 128)] = f2bf(v);
            else              vws[trow * MSGD + (col - 192)] = f2bf(v);
        }
    }
}

// ---------------------------------------------------------------------------
// k_attn (MFMA): 1 block/batch, wave = head. S^T = mfma(K,Q) per 16x16 tile;
// C-layout of S^T (col=q, row k=g*4+r) IS the B-fragment layout of the next
// mfma, so ctx^T = mfma(V^T, P^T) needs no cross-lane repack. V^T staged in
// LDS (pad 132). Softmax over k = 2 shfl_xor (masks 16,32).
// ---------------------------------------------------------------------------
__global__ __launch_bounds__(256) void k_attn(
    const unsigned short* __restrict__ qws, const unsigned short* __restrict__ kws,
    const unsigned short* __restrict__ vws, unsigned short* __restrict__ ctxws)
{
    __shared__ unsigned short vT[64][132];   // [d][token], pad 132
    const int tid = threadIdx.x, b = blockIdx.x;
    const unsigned short* vb = vws + (long)b * NN * MSGD;

    #pragma unroll
    for (int i = 0; i < 4; ++i) {
        int f = tid + i * 256;               // 0..1023
        int tok = f >> 3, d0 = (f & 7) * 8;
        u16x8 v8 = ((const u16x8*)vb)[f];
        #pragma unroll
        for (int j = 0; j < 8; ++j) vT[d0 + j][tok] = v8[j];
    }
    __syncthreads();

    const int lane = tid & 63, h = tid >> 6;
    const int r15 = lane & 15, g = lane >> 4;
    const unsigned short* qb = qws + (long)b * NN * MSGD + h * 16;
    const unsigned short* kb = kws + (long)b * NN * MSGD + h * 16;
    unsigned short* cb = ctxws + (long)b * NN * MSGD + h * 16;

    // K A-fragments: row = k-idx = r15 (per kt tile), k-dim = d = g*4+j
    s16x4 akf[8];
    #pragma unroll
    for (int kt = 0; kt < 8; ++kt)
        akf[kt] = *(const s16x4*)(kb + (kt * 16 + r15) * MSGD + g * 4);
    // V^T A-fragments: row = d = r15, k-dim = token = kt*16 + g*4+j
    s16x4 avf[8];
    #pragma unroll
    for (int kt = 0; kt < 8; ++kt)
        avf[kt] = *(const s16x4*)&vT[h * 16 + r15][kt * 16 + g * 4];

    for (int qh = 0; qh < 2; ++qh) {
        // Q B-fragments: col = q = r15, k-dim = d = g*4+j
        s16x4 qf[4];
        #pragma unroll
        for (int qt = 0; qt < 4; ++qt)
            qf[qt] = *(const s16x4*)(qb + ((qh * 64 + qt * 16 + r15)) * MSGD + g * 4);

        f32x4 zero = (f32x4){0.f, 0.f, 0.f, 0.f};
        f32x4 s[8][4];
        #pragma unroll
        for (int kt = 0; kt < 8; ++kt)
            #pragma unroll
            for (int qt = 0; qt < 4; ++qt)
                s[kt][qt] = MFMA16(akf[kt], qf[qt], zero);

        float il[4];
        #pragma unroll
        for (int qt = 0; qt < 4; ++qt) {
            float m = -1e30f;
            #pragma unroll
            for (int kt = 0; kt < 8; ++kt)
                #pragma unroll
                for (int r = 0; r < 4; ++r) m = fmaxf(m, s[kt][qt][r]);
            m = fmaxf(m, __shfl_xor(m, 16, 64));
            m = fmaxf(m, __shfl_xor(m, 32, 64));
            float l = 0.f;
            #pragma unroll
            for (int kt = 0; kt < 8; ++kt)
                #pragma unroll
                for (int r = 0; r < 4; ++r) {
                    float e = __expf((s[kt][qt][r] - m) * 0.25f);   // scale 1/sqrt(16)
                    s[kt][qt][r] = e;
                    l += e;
                }
            l += __shfl_xor(l, 16, 64);
            l += __shfl_xor(l, 32, 64);
            il[qt] = 1.0f / l;
        }

        f32x4 oacc[4];
        #pragma unroll
        for (int qt = 0; qt < 4; ++qt) oacc[qt] = (f32x4){0.f, 0.f, 0.f, 0.f};
        #pragma unroll
        for (int kt = 0; kt < 8; ++kt)
            #pragma unroll
            for (int qt = 0; qt < 4; ++qt) {
                s16x4 pb;
                #pragma unroll
                for (int r = 0; r < 4; ++r) pb[r] = (short)f2bf(s[kt][qt][r]);
                oacc[qt] = MFMA16(avf[kt], pb, oacc[qt]);
            }

        // ctx^T D-layout: col = q = r15, row = d = g*4+r -> 8B store per qt
        #pragma unroll
        for (int qt = 0; qt < 4; ++qt) {
            u16x4 o4;
            #pragma unroll
            for (int r = 0; r < 4; ++r) o4[r] = f2bf(oacc[qt][r] * il[qt]);
            *(u16x4*)(cb + (qh * 64 + qt * 16 + r15) * MSGD + g * 4) = o4;
        }
    }
}

// ---------------------------------------------------------------------------
// k_integrate: h = LN(obs@iw1_top + ctx@W_fold + b_fold); relu;
//              out = h@iw2 + ib2. MFMA 16x16x32 bf16, LN via 16-lane shfl.
// ---------------------------------------------------------------------------
__global__ __launch_bounds__(256) void k_integrate(
    const float* __restrict__ obs, const unsigned short* __restrict__ ctxws,
    const unsigned short* __restrict__ iw1ts, const unsigned short* __restrict__ wfs,
    const float* __restrict__ bfold, const float* __restrict__ lng,
    const float* __restrict__ lnb, const unsigned short* __restrict__ iw2s,
    const float* __restrict__ ib2, float* __restrict__ out)
{
    __shared__ unsigned short hls[4][16][264];
    const int tid = threadIdx.x, lane = tid & 63, w = tid >> 6;
    const int row = lane & 15, g = lane >> 4;
    const long tok0 = (long)blockIdx.x * 64 + w * 16;

    f32x4 acc[16];
    #pragma unroll
    for (int nt = 0; nt < 16; ++nt) acc[nt] = (f32x4){0.f, 0.f, 0.f, 0.f};

    {
        const float* ap = obs + (tok0 + row) * OBSD + g * 8;
        #pragma unroll
        for (int kk = 0; kk < 4; ++kk) {
            float4 x0 = *(const float4*)(ap + kk * 32);
            float4 x1 = *(const float4*)(ap + kk * 32 + 4);
            s16x8 a;
            a[0] = f2bf(x0.x); a[1] = f2bf(x0.y); a[2] = f2bf(x0.z); a[3] = f2bf(x0.w);
            a[4] = f2bf(x1.x); a[5] = f2bf(x1.y); a[6] = f2bf(x1.z); a[7] = f2bf(x1.w);
            #pragma unroll
            for (int nt = 0; nt < 16; ++nt) {
                s16x8 b = *(const s16x8*)&iw1ts[(((kk << 4) + nt) * 64 + lane) * 8];
                acc[nt] = __builtin_amdgcn_mfma_f32_16x16x32_bf16(a, b, acc[nt], 0, 0, 0);
            }
        }
    }
    {
        const unsigned short* cp = ctxws + (tok0 + row) * MSGD + g * 8;
        #pragma unroll
        for (int kk = 0; kk < 2; ++kk) {
            s16x8 a = *(const s16x8*)(cp + kk * 32);
            #pragma unroll
            for (int nt = 0; nt < 16; ++nt) {
                s16x8 b = *(const s16x8*)&wfs[(((kk << 4) + nt) * 64 + lane) * 8];
                acc[nt] = __builtin_amdgcn_mfma_f32_16x16x32_bf16(a, b, acc[nt], 0, 0, 0);
            }
        }
    }

    float xs[4] = {}, xs2[4] = {};
    #pragma unroll
    for (int nt = 0; nt < 16; ++nt) {
        float bias = bfold[nt * 16 + row];
        #pragma unroll
        for (int r = 0; r < 4; ++r) {
            float v = acc[nt][r] + bias;
            acc[nt][r] = v;
            xs[r] += v;
            xs2[r] = fmaf(v, v, xs2[r]);
        }
    }
    #pragma unroll
    for (int r = 0; r < 4; ++r) {
        #pragma unroll
        for (int m = 1; m < 16; m <<= 1) {
            xs[r]  += __shfl_xor(xs[r],  m, 64);
            xs2[r] += __shfl_xor(xs2[r], m, 64);
        }
    }
    float mu[4], rstd[4];
    #pragma unroll
    for (int r = 0; r < 4; ++r) {
        mu[r] = xs[r] * (1.0f / IHID);
        float var = xs2[r] * (1.0f / IHID) - mu[r] * mu[r];
        rstd[r] = rsqrtf(var + 1e-5f);
    }
    #pragma unroll
    for (int nt = 0; nt < 16; ++nt) {
        float gg = lng[nt * 16 + row], bb = lnb[nt * 16 + row];
        #pragma unroll
        for (int r = 0; r < 4; ++r) {
            float v = fmaf((acc[nt][r] - mu[r]) * rstd[r], gg, bb);
            hls[w][g * 4 + r][nt * 16 + row] = f2bf(fmaxf(v, 0.f));
        }
    }
    __syncthreads();

    f32x4 acc2[8];
    #pragma unroll
    for (int nt = 0; nt < 8; ++nt) acc2[nt] = (f32x4){0.f, 0.f, 0.f, 0.f};
    #pragma unroll
    for (int kk = 0; kk < 8; ++kk) {
        s16x8 a = *(const s16x8*)&hls[w][row][kk * 32 + g * 8];
        #pragma unroll
        for (int nt = 0; nt < 8; ++nt) {
            s16x8 b = *(const s16x8*)&iw2s[(((kk << 3) + nt) * 64 + lane) * 8];
            acc2[nt] = __builtin_amdgcn_mfma_f32_16x16x32_bf16(a, b, acc2[nt], 0, 0, 0);
        }
    }
    #pragma unroll
    for (int nt = 0; nt < 8; ++nt) {
        int col = nt * 16 + row;
        float bias = ib2[col];
        #pragma unroll
        for (int r = 0; r < 4; ++r)
            out[(tok0 + g * 4 + r) * OBSD + col] = acc2[nt][r] + bias;
    }
}

// ---------------------------------------------------------------------------
extern "C" void kernel_launch(void* const* d_in, const int* in_sizes, int n_in,
                              void* d_out, int out_size, void* d_ws, size_t ws_size,
                              hipStream_t stream)
{
    (void)in_sizes; (void)n_in; (void)out_size; (void)ws_size;

    const float* obs = (const float*)d_in[0];
    const float* ew1 = (const float*)d_in[1];
    const float* eb1 = (const float*)d_in[2];
    const float* ew2 = (const float*)d_in[3];
    const float* eb2 = (const float*)d_in[4];
    const float* wq  = (const float*)d_in[5];
    const float* bq  = (const float*)d_in[6];
    const float* wk  = (const float*)d_in[7];
    const float* bk  = (const float*)d_in[8];
    const float* wv  = (const float*)d_in[9];
    const float* bv  = (const float*)d_in[10];
    const float* wo  = (const float*)d_in[11];
    const float* bo  = (const float*)d_in[12];
    const float* iw1 = (const float*)d_in[13];
    const float* ib1 = (const float*)d_in[14];
    const float* lng = (const float*)d_in[15];
    const float* lnb = (const float*)d_in[16];
    const float* iw2 = (const float*)d_in[17];
    const float* ib2 = (const float*)d_in[18];

    float* enriched = (float*)d_out;
    float* msgs     = enriched + (size_t)BB * NN * OBSD;

    float* wsf = (float*)d_ws;
    unsigned short* wsu = (unsigned short*)(wsf + 41472);
    unsigned short* ew1s  = wsu;
    unsigned short* wcats = wsu + 16384;
    unsigned short* iw1ts = wsu + 49152;
    unsigned short* wfs   = wsu + 81920;
    unsigned short* iw2s  = wsu + 98304;
    unsigned short* qws   = wsu + 131072;
    unsigned short* kws   = qws + (size_t)BB * NN * MSGD;
    unsigned short* vws   = kws + (size_t)BB * NN * MSGD;
    unsigned short* ctxws = vws + (size_t)BB * NN * MSGD;

    const float* bcat  = wsf + 40960;
    const float* bfold = wsf + 41216;

    k_prep1<<<162, 256, 0, stream>>>(ew2, eb2, wq, bq, wk, bk, wv, bv,
                                     wo, bo, iw1, ib1, wsf);
    k_prep2<<<256, 512, 0, stream>>>(ew1, ew2, iw1, iw2, wsf, wsu);
    k_encoder<<<BB * NN / 64, 256, 0, stream>>>(obs, ew1s, eb1, wcats, bcat,
                                                msgs, qws, kws, vws);
    k_attn<<<BB, 256, 0, stream>>>(qws, kws, vws, ctxws);
    k_integrate<<<BB * NN / 64, 256, 0, stream>>>(obs, ctxws, iw1ts, wfs, bfold,
                                                  lng, lnb, iw2s, ib2, enriched);
}